// Round 5
// baseline (733.325 us; speedup 1.0000x reference)
//
#include <hip/hip_runtime.h>
#include <cstddef>

#define HH 16
#define TT 512
#define STG 16           // timesteps per LDS x-stage
#define NSTG (TT / STG)  // 32 stages
#define LOG2E 1.44269504088896340736f

typedef float v4f __attribute__((ext_vector_type(4)));

static __device__ __forceinline__ float fexp2(float x){ return __builtin_amdgcn_exp2f(x); }
static __device__ __forceinline__ float frcp (float x){ return __builtin_amdgcn_rcpf(x); }
static __device__ __forceinline__ float frsq (float x){ return __builtin_amdgcn_rsqf(x); }

// tanh(c) = 2/(1+exp(-2c)) - 1 ; saturates correctly (rcp(inf)=0)
static __device__ __forceinline__ float ftanh(float c){
    return frcp(1.0f + fexp2(c * (-2.0f*LOG2E))) * 2.0f - 1.0f;
}

// broadcast within each quad of lanes (VALU DPP)
template<int CTRL>
static __device__ __forceinline__ float qb(float v){
    return __builtin_bit_cast(float,
        __builtin_amdgcn_update_dpp(0, __builtin_bit_cast(int,v), CTRL, 0xF, 0xF, true));
}

// force a plain full-rate scalar FMA: v_fmac_f32 d, a, b  (d += a*b)
static __device__ __forceinline__ void fm(float& d, float a, float b){
    asm("v_fmac_f32 %0, %1, %2" : "+v"(d) : "v"(a), "v"(b));
}

// 16-MAC fp32 dot, 4 independent accumulator chains, via v_fmac_f32
static __device__ __forceinline__ void fmac16(const v4f* a, const v4f* w,
                                              float& s0, float& s1, float& s2, float& s3){
    fm(s0, a[0].x, w[0].x); fm(s1, a[0].y, w[0].y);
    fm(s2, a[0].z, w[0].z); fm(s3, a[0].w, w[0].w);
    fm(s0, a[1].x, w[1].x); fm(s1, a[1].y, w[1].y);
    fm(s2, a[1].z, w[1].z); fm(s3, a[1].w, w[1].w);
    fm(s0, a[2].x, w[2].x); fm(s1, a[2].y, w[2].y);
    fm(s2, a[2].z, w[2].z); fm(s3, a[2].w, w[2].w);
    fm(s0, a[3].x, w[3].x); fm(s1, a[3].y, w[3].y);
    fm(s2, a[3].z, w[3].z); fm(s3, a[3].w, w[3].w);
}

static __device__ __forceinline__ void ld4(v4f* dst, const float* p){
    const v4f* q = (const v4f*)p;
    dst[0] = q[0]; dst[1] = q[1]; dst[2] = q[2]; dst[3] = q[3];
}

// One wave per batch element. Lane l owns gate g=l&3 of hidden unit k=l>>2.
// All math fp32 (the 512-step recurrence amplifies per-step noise ~1e4x, so
// f16/bf16 inputs fail validation — measured R4). Layer 1 pipelined one step
// ahead of layer 2 so LDS broadcast round-trips overlap VALU work.
__global__ __launch_bounds__(256, 4) void lstm_fused_kernel(
    const float* __restrict__ x,
    const float* __restrict__ W_ih0, const float* __restrict__ W_hh0,
    const float* __restrict__ b_ih0, const float* __restrict__ b_hh0,
    const float* __restrict__ W_ih1, const float* __restrict__ W_hh1,
    const float* __restrict__ b_ih1, const float* __restrict__ b_hh1,
    const float* __restrict__ W_proj, const float* __restrict__ b_proj,
    const float* __restrict__ ln_g, const float* __restrict__ ln_b,
    float* __restrict__ out)
{
    const int lane = threadIdx.x & 63;
    const int wave = threadIdx.x >> 6;
    const int b    = blockIdx.x * 4 + wave;

    const int g   = lane & 3;        // 0=i 1=f 2=g 3=o
    const int k   = lane >> 2;       // hidden unit 0..15
    const int row = g * HH + k;      // row in [4H,H] weights (PyTorch order)

    // per-wave LDS: two 256-float x-stages (ping-pong) + h1[16] + h2[16]
    __shared__ float sh[4 * 544];
    float* xb0 = sh + wave * 544;
    float* xb1 = xb0 + 256;
    float* h1w = xb1 + 256;
    float* h2w = h1w + 16;

    // ---- weights into VGPRs (one-time) ----
    v4f wih0[4], whh0[4], wih1[4], whh1[4];
#pragma unroll
    for (int q = 0; q < 4; ++q) {
        wih0[q] = ((const v4f*)(W_ih0 + row * HH))[q];
        whh0[q] = ((const v4f*)(W_hh0 + row * HH))[q];
        wih1[q] = ((const v4f*)(W_ih1 + row * HH))[q];
        whh1[q] = ((const v4f*)(W_hh1 + row * HH))[q];
    }
    const float bias0 = b_ih0[row] + b_hh0[row];
    const float bias1 = b_ih1[row] + b_hh1[row];

    // activation constants: sigmoid for i,f,o ; tanh for g (=2*sig(2x)-1)
    const bool  isg    = (g == 2);
    const float sc_in  = isg ? (-2.0f * LOG2E) : (-LOG2E);
    const float sc_out = isg ? 2.0f : 1.0f;
    const float sh_out = isg ? 1.0f : 0.0f;

    const float* xg = x + (size_t)b * TT * HH;

    // ================= prologue =================
    v4f xs = *(const v4f*)(xg + lane * 4);     // global stage 0
    *(v4f*)(xb0 + lane * 4) = xs;              // LDS stage 0
    xs = *(const v4f*)(xg + 256 + lane * 4);   // prefetch global stage 1

    v4f xa[4];
    ld4(xa, xb0);                              // broadcast x(0)

    float c1, c2 = 0.0f;
    v4f h1a[4], h2a[4];
#pragma unroll
    for (int q = 0; q < 4; ++q) h2a[q] = (v4f)(0.f);

    // layer-1 step 0 (h1(-1) = 0: skip hh dot)
    {
        float s0 = bias0, s1 = 0.f, s2 = 0.f, s3 = 0.f;
        fmac16(xa, wih0, s0, s1, s2, s3);
        float a1 = (s0 + s1) + (s2 + s3);
        float act1 = frcp(1.0f + fexp2(a1 * sc_in)) * sc_out - sh_out;
        float i1 = qb<0x00>(act1), g1 = qb<0xAA>(act1), o1 = qb<0xFF>(act1);
        c1 = i1 * g1;
        float h1n = o1 * ftanh(c1);
        h1w[k] = h1n;
        ld4(h1a, h1w);                         // broadcast h1(0)
        ld4(xa, xb0 + HH);                     // broadcast x(1)
    }

    // ================= main loop =================
    // iter t: layer1 computes h1(t+1) [xa=x(t+1), h1a=h1(t)];
    //         layer2 computes h2(t)   [h1a=h1(t), h2a=h2(t-1)]
    for (int s = 0; s < NSTG; ++s) {
        float* cur = (s & 1) ? xb1 : xb0;
        float* nxt = (s & 1) ? xb0 : xb1;

        *(v4f*)(nxt + lane * 4) = xs;          // LDS stage s+1
        const int sp = (s + 2 < NSTG) ? (s + 2) : (NSTG - 1);
        xs = *(const v4f*)(xg + (size_t)sp * 256 + lane * 4);  // prefetch s+2

#pragma unroll
        for (int ti = 0; ti < STG; ++ti) {
            // ---- layer 1, step t+1 ----
            float s0 = bias0, s1 = 0.f, s2 = 0.f, s3 = 0.f;
            fmac16(xa,  wih0, s0, s1, s2, s3);
            fmac16(h1a, whh0, s0, s1, s2, s3);
            float a1 = (s0 + s1) + (s2 + s3);
            float act1 = frcp(1.0f + fexp2(a1 * sc_in)) * sc_out - sh_out;
            float i1 = qb<0x00>(act1), f1 = qb<0x55>(act1);
            float g1 = qb<0xAA>(act1), o1 = qb<0xFF>(act1);
            c1 = __builtin_fmaf(f1, c1, i1 * g1);
            float h1n = o1 * ftanh(c1);
            h1w[k] = h1n;                      // publish h1(t+1)

            // ---- layer 2 part A: h1(t) . W_ih1 (last use of old h1a) ----
            float q0 = bias1, q1 = 0.f, q2 = 0.f, q3 = 0.f;
            fmac16(h1a, wih1, q0, q1, q2, q3);

            ld4(h1a, h1w);                     // broadcast h1(t+1)  [next iter]
            // broadcast x(t+2) [next iter]; ti is compile-time (unrolled)
            ld4(xa, (ti <= 13) ? (cur + (ti + 2) * HH) : (nxt + (ti - 14) * HH));

            // ---- layer 2 part B: h2(t-1) . W_hh1 ----
            fmac16(h2a, whh1, q0, q1, q2, q3);
            float a2 = (q0 + q1) + (q2 + q3);
            float act2 = frcp(1.0f + fexp2(a2 * sc_in)) * sc_out - sh_out;
            float i2 = qb<0x00>(act2), f2 = qb<0x55>(act2);
            float g2 = qb<0xAA>(act2), o2 = qb<0xFF>(act2);
            c2 = __builtin_fmaf(f2, c2, i2 * g2);
            float h2n = o2 * ftanh(c2);
            h2w[k] = h2n;                      // publish h2(t)
            ld4(h2a, h2w);                     // broadcast h2(t)    [next iter]
        }
    }

    // ---- epilogue: z = h2(T-1) @ W_proj^T + b_proj ; LayerNorm ; tanh ----
    const int u = lane & 15;   // output unit (replicated x4 across the wave)
    v4f wp[4];
#pragma unroll
    for (int q = 0; q < 4; ++q) wp[q] = ((const v4f*)(W_proj + u * HH))[q];
    float s0 = b_proj[u], s1 = 0.f, s2 = 0.f, s3 = 0.f;
    fmac16(h2a, wp, s0, s1, s2, s3);
    float z = (s0 + s1) + (s2 + s3);

    // stats across the 16-lane group (xor masks 1,2,4,8 stay in-group)
    float sacc = z;
    sacc += __shfl_xor(sacc, 1); sacc += __shfl_xor(sacc, 2);
    sacc += __shfl_xor(sacc, 4); sacc += __shfl_xor(sacc, 8);
    const float mu = sacc * (1.0f / 16.0f);

    const float d = z - mu;
    float qq = d * d;
    qq += __shfl_xor(qq, 1); qq += __shfl_xor(qq, 2);
    qq += __shfl_xor(qq, 4); qq += __shfl_xor(qq, 8);
    const float var = qq * (1.0f / 16.0f);

    const float rs  = frsq(var + 1e-5f);
    const float y   = d * rs * ln_g[u] + ln_b[u];
    const float res = ftanh(y);

    if (lane < 16) out[(size_t)b * HH + lane] = res;
}

extern "C" void kernel_launch(void* const* d_in, const int* in_sizes, int n_in,
                              void* d_out, int out_size, void* d_ws, size_t ws_size,
                              hipStream_t stream) {
    const float* x      = (const float*)d_in[0];
    const float* W_ih0  = (const float*)d_in[1];
    const float* W_hh0  = (const float*)d_in[2];
    const float* b_ih0  = (const float*)d_in[3];
    const float* b_hh0  = (const float*)d_in[4];
    const float* W_ih1  = (const float*)d_in[5];
    const float* W_hh1  = (const float*)d_in[6];
    const float* b_ih1  = (const float*)d_in[7];
    const float* b_hh1  = (const float*)d_in[8];
    const float* W_proj = (const float*)d_in[9];
    const float* b_proj = (const float*)d_in[10];
    const float* ln_g   = (const float*)d_in[11];
    const float* ln_b   = (const float*)d_in[12];
    float* out = (float*)d_out;

    const int B = in_sizes[0] / (TT * HH);   // 4096
    dim3 grid(B / 4), block(256);            // one wave per batch element
    hipLaunchKernelGGL(lstm_fused_kernel, grid, block, 0, stream,
                       x, W_ih0, W_hh0, b_ih0, b_hh0,
                       W_ih1, W_hh1, b_ih1, b_hh1,
                       W_proj, b_proj, ln_g, ln_b, out);
}